// Round 13
// baseline (244.958 us; speedup 1.0000x reference)
//
#include <hip/hip_runtime.h>

// R13 = ABLATION ROUND. R10-R12 all flat at ~42us chamfer vs 13.6us MFMA
// floor; three theories unresolved. One templated kernel, 3 dispatches:
//  MODE 0 (REP 2): real R12 kernel, t-loop x2 (min idempotent -> correct,
//                  and ~80us puts it in rocprof top-5 for counters).
//  MODE 1 (REP 4): MFMA-only, VGPR ping-pong D (R12 core, fold -> 1 min3
//                  liveness op). Isolates separate-VGPR-D MFMA throughput.
//  MODE 2 (REP 4): AGPR in-place accumulate acc=mfma(a,b,acc) (ubench
//                  pattern, m119) -> sanity anchor for the 13.6us floor.
// V1/V2 write to d_ws scratch; only MODE 0 writes d_out (unchanged math).

typedef __attribute__((ext_vector_type(8))) short  s16x8;
typedef __attribute__((ext_vector_type(16))) float f32x16;
typedef unsigned int u32;

#define TSLICE 512    // targets staged in LDS per block (16 KB packed)
#define QPB    512    // queries per block (4 waves x 128)
#define QPW    128    // queries per wave (4 frags of 32)

__device__ inline u32 umin3(u32 a, u32 b, u32 c) {
    const u32 t = a < b ? a : b;
    return t < c ? t : c;           // -> v_min3_u32
}

// R12's fused step: MFMA into fresh D; fold PREVIOUS D (>=26cy old) into
// best with 8 v_min3_u32 in the MFMA's shadow; trailing s_nop pads the
// next block's first read of our D.
__device__ inline f32x16 mfma_fold(const s16x8 a, const s16x8 b, const f32x16 c,
                                   const f32x16 p, u32& best) {
    f32x16 d;
    u32 t0, t1, t2, t3, t4;
    asm("v_mfma_f32_32x32x16_bf16 %0, %7, %8, %9\n\t"
        "v_min3_u32 %2, %10, %11, %12\n\t"
        "v_min3_u32 %3, %13, %14, %15\n\t"
        "v_min3_u32 %4, %16, %17, %18\n\t"
        "v_min3_u32 %5, %19, %20, %21\n\t"
        "v_min3_u32 %6, %22, %23, %24\n\t"
        "v_min3_u32 %2, %2, %3, %25\n\t"
        "v_min3_u32 %4, %4, %5, %6\n\t"
        "v_min3_u32 %1, %2, %4, %1\n\t"
        "s_nop 7"
        : "=&v"(d), "+v"(best),
          "=&v"(t0), "=&v"(t1), "=&v"(t2), "=&v"(t3), "=&v"(t4)
        : "v"(a), "v"(b), "v"(c),
          "v"(p[0]),  "v"(p[1]),  "v"(p[2]),  "v"(p[3]),
          "v"(p[4]),  "v"(p[5]),  "v"(p[6]),  "v"(p[7]),
          "v"(p[8]),  "v"(p[9]),  "v"(p[10]), "v"(p[11]),
          "v"(p[12]), "v"(p[13]), "v"(p[14]), "v"(p[15]));
    return d;
}

// V1: MFMA-only with the same ping-pong D; 1 min3 on the previous D keeps
// everything live (rule 17) without the 8-op fold.
__device__ inline f32x16 mfma_nofold(const s16x8 a, const s16x8 b, const f32x16 c,
                                     const f32x16 p, u32& best) {
    f32x16 d;
    asm("v_mfma_f32_32x32x16_bf16 %0, %2, %3, %4\n\t"
        "v_min3_u32 %1, %5, %6, %1\n\t"
        "s_nop 7\n\ts_nop 7"
        : "=&v"(d), "+v"(best)
        : "v"(a), "v"(b), "v"(c), "v"(p[0]), "v"(p[1]));
    return d;
}

// ---------- bf16 split helper (bit-level, RNE) ----------
__device__ inline unsigned int bf16bits(float v, float &hival) {
    unsigned int u = __float_as_uint(v);
    unsigned int r = (u + 0x7FFFu + ((u >> 16) & 1u)) >> 16;
    hival = __uint_as_float(r << 16);
    return r;
}

// ---------- fused pre-pass: pack both inputs + sentinel-init d_out ----------
__global__ __launch_bounds__(256)
void pack_all_kernel(const float* __restrict__ in1, const float* __restrict__ in2,
                     ushort* __restrict__ A1, ushort* __restrict__ B1, float* __restrict__ S1,
                     ushort* __restrict__ A2, ushort* __restrict__ B2, float* __restrict__ S2,
                     unsigned int* __restrict__ out, int P1, int P2) {
    const int g = blockIdx.x * 256 + threadIdx.x;
    if (g >= P1 + P2) return;
    out[g] = 0x7F7F7F7Fu;                 // 3.39e38f sentinel (flat over both outs)

    const float* src; ushort* pA; ushort* pB; float* sq; int p;
    if (g < P1) { src = in1; pA = A1; pB = B1; sq = S1; p = g; }
    else        { src = in2; pA = A2; pB = B2; sq = S2; p = g - P1; }

    const float x = src[3*p+0], y = src[3*p+1], z = src[3*p+2];
    float xhf, xlf, yhf, ylf, zhf, zlf, shf, tmp;
    const ushort xh = (ushort)bf16bits(x, xhf);
    const ushort xl = (ushort)bf16bits(x - xhf, xlf);
    const ushort yh = (ushort)bf16bits(y, yhf);
    const ushort yl = (ushort)bf16bits(y - yhf, ylf);
    const ushort zh = (ushort)bf16bits(z, zhf);
    const ushort zl = (ushort)bf16bits(z - zhf, zlf);
    const float s = fmaf(x, x, fmaf(y, y, z * z));
    const ushort sh = (ushort)bf16bits(s, shf);
    const ushort sl = (ushort)bf16bits(s - shf, tmp);
    const ushort m2xh = (ushort)bf16bits(-2.0f * xhf, tmp);
    const ushort m2xl = (ushort)bf16bits(-2.0f * xlf, tmp);
    const ushort m2yh = (ushort)bf16bits(-2.0f * yhf, tmp);
    const ushort m2yl = (ushort)bf16bits(-2.0f * ylf, tmp);
    const ushort m2zh = (ushort)bf16bits(-2.0f * zhf, tmp);
    const ushort m2zl = (ushort)bf16bits(-2.0f * zlf, tmp);
    const ushort ONE  = 0x3F80;           // 1.0 bf16
    const ushort BIAS = 0x4400;           // 512.0 bf16 (exact)

    const s16x8 a0 = {(short)m2xh,(short)m2xl,(short)m2xh,(short)m2xl,
                      (short)m2yh,(short)m2yl,(short)m2yh,(short)m2yl};
    const s16x8 a1 = {(short)m2zh,(short)m2zl,(short)m2zh,(short)m2zl,
                      (short)sh,  (short)sl,  (short)BIAS, 0};
    const s16x8 b0 = {(short)xh,(short)xh,(short)xl,(short)xl,
                      (short)yh,(short)yh,(short)yl,(short)yl};
    const s16x8 b1 = {(short)zh,(short)zh,(short)zl,(short)zl,
                      (short)ONE,(short)ONE,(short)ONE, 0};

    s16x8* A8 = (s16x8*)pA;
    s16x8* B8 = (s16x8*)pB;
    const int c0 = (p & ~31) * 2 + (p & 31);
    A8[c0]      = a0;   // k-slots 0-7  (lanes 0-31)
    A8[c0 + 32] = a1;   // k-slots 8-15 (lanes 32-63)
    B8[2*p]     = b0;
    B8[2*p + 1] = b1;
    sq[p] = s;
}

// ---------- main kernel, templated ablation ----------
template<int MODE, int REP>
__global__ __launch_bounds__(256)
void chamfer_mfma_kernel(const ushort* __restrict__ Ad1, const ushort* __restrict__ Bd1,
                         const float*  __restrict__ Sd1, unsigned int* __restrict__ Od1,
                         const ushort* __restrict__ Ad2, const ushort* __restrict__ Bd2,
                         const float*  __restrict__ Sd2, unsigned int* __restrict__ Od2,
                         unsigned int* __restrict__ outv, int Np, int Mp) {
    __shared__ s16x8 lds8[TSLICE * 2];   // 16 KB
    const int z = blockIdx.z;
    const ushort* pA  = z ? Ad2 : Ad1;
    const ushort* pB  = z ? Bd2 : Bd1;
    const float*  sqq = z ? Sd2 : Sd1;
    unsigned int* out = z ? Od2 : Od1;

    const int tid  = threadIdx.x;
    const int lane = tid & 63;
    const int wid  = tid >> 6;
    const int qblock = blockIdx.x * QPB;
    const int b = qblock / Np;
    const size_t gchunk = ((size_t)b * Mp + (size_t)blockIdx.y * TSLICE) * 2;
    const s16x8* gA = (const s16x8*)pA + gchunk;
    for (int i = tid; i < TSLICE * 2; i += 256) lds8[i] = gA[i];

    const int qw = qblock + wid * QPW;
    s16x8 bfr[4];
    #pragma unroll
    for (int f = 0; f < 4; ++f) {
        const int q = qw + f * 32 + (lane & 31);
        bfr[f] = *(const s16x8*)(pB + (size_t)q * 16 + (size_t)(lane >> 5) * 8);
    }
    __syncthreads();

    const int NT = TSLICE / 32;

    if constexpr (MODE == 2) {
        // AGPR in-place accumulate (ubench pattern): pure MFMA pipe probe.
        f32x16 acc = {0.f,0.f,0.f,0.f,0.f,0.f,0.f,0.f,
                      0.f,0.f,0.f,0.f,0.f,0.f,0.f,0.f};
        for (int r = 0; r < REP; ++r) {
            s16x8 a = lds8[lane];
            for (int t = 0; t < NT; ++t) {
                const int tn = (t + 1 < NT) ? (t + 1) : t;
                const s16x8 an = lds8[tn * 64 + lane];
                asm("v_mfma_f32_32x32x16_bf16 %0, %1, %2, %0" : "+a"(acc) : "v"(a), "v"(bfr[0]));
                asm("v_mfma_f32_32x32x16_bf16 %0, %1, %2, %0" : "+a"(acc) : "v"(a), "v"(bfr[1]));
                asm("v_mfma_f32_32x32x16_bf16 %0, %1, %2, %0" : "+a"(acc) : "v"(a), "v"(bfr[2]));
                asm("v_mfma_f32_32x32x16_bf16 %0, %1, %2, %0" : "+a"(acc) : "v"(a), "v"(bfr[3]));
                a = an;
            }
        }
        asm("s_nop 7\n\ts_nop 7\n\ts_nop 7" : "+a"(acc));  // guard C-reads of acc
        u32 x = 0;
        #pragma unroll
        for (int i = 0; i < 16; ++i) x ^= __float_as_uint(acc[i]);
        const size_t idx = (((size_t)blockIdx.z * gridDim.y + blockIdx.y) * gridDim.x
                            + blockIdx.x) * 256 + tid;
        outv[idx] = x;
        return;
    }

    f32x16 cz = {0.f,0.f,0.f,0.f,0.f,0.f,0.f,0.f,
                 0.f,0.f,0.f,0.f,0.f,0.f,0.f,0.f};
    asm("" : "+v"(cz));   // pin as live VGPR tuple

    u32 bests[4] = {0x7F7F7F7Fu, 0x7F7F7F7Fu, 0x7F7F7F7Fu, 0x7F7F7F7Fu};
    const float SENT = __uint_as_float(0x7F7F7F7Fu);
    f32x16 dprev = {SENT,SENT,SENT,SENT,SENT,SENT,SENT,SENT,
                    SENT,SENT,SENT,SENT,SENT,SENT,SENT,SENT};

    for (int r = 0; r < REP; ++r) {
        s16x8 a = lds8[lane];
        for (int t = 0; t < NT; ++t) {
            const int tn = (t + 1 < NT) ? (t + 1) : t;
            const s16x8 an = lds8[tn * 64 + lane];
            if constexpr (MODE == 0) {
                dprev = mfma_fold(a, bfr[0], cz, dprev, bests[3]);
                dprev = mfma_fold(a, bfr[1], cz, dprev, bests[0]);
                dprev = mfma_fold(a, bfr[2], cz, dprev, bests[1]);
                dprev = mfma_fold(a, bfr[3], cz, dprev, bests[2]);
            } else {  // MODE 1
                dprev = mfma_nofold(a, bfr[0], cz, dprev, bests[3]);
                dprev = mfma_nofold(a, bfr[1], cz, dprev, bests[0]);
                dprev = mfma_nofold(a, bfr[2], cz, dprev, bests[1]);
                dprev = mfma_nofold(a, bfr[3], cz, dprev, bests[2]);
            }
            a = an;
        }
    }

    asm("s_nop 7\n\ts_nop 7\n\ts_nop 7" : "+v"(dprev));  // guard final D reads

    if constexpr (MODE == 0) {
        {   // fold the final tile (belongs to frag 3)
            const u32 m0 = umin3(__float_as_uint(dprev[0]),  __float_as_uint(dprev[1]),  __float_as_uint(dprev[2]));
            const u32 m1 = umin3(__float_as_uint(dprev[3]),  __float_as_uint(dprev[4]),  __float_as_uint(dprev[5]));
            const u32 m2 = umin3(__float_as_uint(dprev[6]),  __float_as_uint(dprev[7]),  __float_as_uint(dprev[8]));
            const u32 m3 = umin3(__float_as_uint(dprev[9]),  __float_as_uint(dprev[10]), __float_as_uint(dprev[11]));
            const u32 m4 = umin3(__float_as_uint(dprev[12]), __float_as_uint(dprev[13]), __float_as_uint(dprev[14]));
            const u32 m5 = umin3(m0, m1, __float_as_uint(dprev[15]));
            const u32 m6 = umin3(m2, m3, m4);
            bests[3] = umin3(m5, m6, bests[3]);
        }
        #pragma unroll
        for (int f = 0; f < 4; ++f) {
            u32 bu = bests[f];
            const u32 other = __shfl_xor(bu, 32);
            bu = bu < other ? bu : other;
            const int q = qw + f * 32 + (lane & 31);
            float v = (__uint_as_float(bu) - 512.0f) + sqq[q];
            v = fmaxf(v, 0.0f);
            if (lane < 32) atomicMin(out + q, __float_as_uint(v));
        }
    } else {
        u32 x = bests[0] ^ bests[1] ^ bests[2] ^ bests[3];
        #pragma unroll
        for (int i = 0; i < 16; ++i) x ^= __float_as_uint(dprev[i]);
        const size_t idx = (((size_t)blockIdx.z * gridDim.y + blockIdx.y) * gridDim.x
                            + blockIdx.x) * 256 + tid;
        outv[idx] = x;
    }
}

// ---------- fallback (round-2 VALU kernel) if ws too small ----------
#define FSLICE 512
#define FROWS  512
__global__ __launch_bounds__(256)
void chamfer_dir_kernel(const float* __restrict__ P, const float* __restrict__ Q,
                        unsigned int* __restrict__ out, int Np, int Mp) {
    __shared__ float4 lds[FSLICE];
    const int tid = threadIdx.x;
    const int rowBase = blockIdx.x * FROWS;
    const int b = rowBase / Np;
    const int slice0 = blockIdx.y * FSLICE;
    const float* qs = Q + ((size_t)b * Mp + slice0) * 3;
    #pragma unroll
    for (int i = tid; i < FSLICE; i += 256) {
        const float x = qs[3*i+0], y = qs[3*i+1], z = qs[3*i+2];
        lds[i] = make_float4(x, y, z, fmaf(x, x, fmaf(y, y, z * z)));
    }
    const int q0 = rowBase + tid, q1 = q0 + 256;
    const float* p0 = P + (size_t)q0 * 3;
    const float* p1 = P + (size_t)q1 * 3;
    const float x0=p0[0], y0=p0[1], z0=p0[2], x1=p1[0], y1=p1[1], z1=p1[2];
    const float m2x0=-2*x0, m2y0=-2*y0, m2z0=-2*z0, m2x1=-2*x1, m2y1=-2*y1, m2z1=-2*z1;
    const float sqp0 = fmaf(x0,x0,fmaf(y0,y0,z0*z0));
    const float sqp1 = fmaf(x1,x1,fmaf(y1,y1,z1*z1));
    __syncthreads();
    float best0 = 3.0e38f, best1 = 3.0e38f;
    #pragma unroll 4
    for (int j = 0; j < FSLICE; j += 2) {
        const float4 a = lds[j], c = lds[j+1];
        const float d00 = fmaf(m2x0,a.x,fmaf(m2y0,a.y,fmaf(m2z0,a.z,a.w)));
        const float d01 = fmaf(m2x0,c.x,fmaf(m2y0,c.y,fmaf(m2z0,c.z,c.w)));
        best0 = fminf(fminf(d00,d01), best0);
        const float d10 = fmaf(m2x1,a.x,fmaf(m2y1,a.y,fmaf(m2z1,a.z,a.w)));
        const float d11 = fmaf(m2x1,c.x,fmaf(m2y1,c.y,fmaf(m2z1,c.z,c.w)));
        best1 = fminf(fminf(d10,d11), best1);
    }
    atomicMin(out + q0, __float_as_uint(fmaxf(best0 + sqp0, 0.f)));
    atomicMin(out + q1, __float_as_uint(fmaxf(best1 + sqp1, 0.f)));
}

extern "C" void kernel_launch(void* const* d_in, const int* in_sizes, int n_in,
                              void* d_out, int out_size, void* d_ws, size_t ws_size,
                              hipStream_t stream) {
    const float* in1 = (const float*)d_in[0];   // [B, N, 3]
    const float* in2 = (const float*)d_in[1];   // [B, M, 3]
    const int B = 8;
    const int N = in_sizes[0] / (B * 3);
    const int M = in_sizes[1] / (B * 3);
    const int P1 = B * N, P2 = B * M;
    unsigned int* out = (unsigned int*)d_out;

    const size_t packBytes1 = (size_t)P1 * 32, packBytes2 = (size_t)P2 * 32;
    const size_t needPack = 2*packBytes1 + 2*packBytes2 + (size_t)(P1+P2)*4;

    if (ws_size >= needPack && N == M) {
        char* w = (char*)d_ws;
        ushort* A1 = (ushort*)(w);
        ushort* B1 = (ushort*)(w + packBytes1);
        ushort* A2 = (ushort*)(w + 2*packBytes1);
        ushort* B2 = (ushort*)(w + 2*packBytes1 + packBytes2);
        float*  S1 = (float*) (w + 2*packBytes1 + 2*packBytes2);
        float*  S2 = (float*) (w + 2*packBytes1 + 2*packBytes2 + (size_t)P1*4);

        pack_all_kernel<<<(P1 + P2 + 255)/256, 256, 0, stream>>>(
            in1, in2, A1, B1, S1, A2, B2, S2, out, P1, P2);

        dim3 g(P1 / QPB, M / TSLICE, 2);
        // V0: the real kernel (REP=2; min-fold idempotent -> same output).
        chamfer_mfma_kernel<0, 2><<<g, 256, 0, stream>>>(
            A2, B1, S1, out, A1, B2, S2, out + P1, nullptr, N, M);

        // Ablation probes -> d_ws scratch (4 MB region after pack data).
        const size_t ablBytes = (size_t)g.x * g.y * g.z * 256 * 4;
        if (ws_size >= needPack + ablBytes) {
            unsigned int* wsv = (unsigned int*)(w + needPack);
            chamfer_mfma_kernel<1, 4><<<g, 256, 0, stream>>>(
                A2, B1, S1, out, A1, B2, S2, out + P1, wsv, N, M);
            chamfer_mfma_kernel<2, 4><<<g, 256, 0, stream>>>(
                A2, B1, S1, out, A1, B2, S2, out + P1, wsv, N, M);
        }
    } else {
        hipMemsetAsync(d_out, 0x7F, (size_t)out_size * sizeof(float), stream);
        dim3 g1(P1 / FROWS, M / FSLICE);
        chamfer_dir_kernel<<<g1, 256, 0, stream>>>(in1, in2, out, N, M);
        dim3 g2(P2 / FROWS, N / FSLICE);
        chamfer_dir_kernel<<<g2, 256, 0, stream>>>(in2, in1, out + P1, M, N);
    }
}

// Round 14
// 46.587 us; speedup vs baseline: 5.2581x; 5.2581x over previous
//
#include <hip/hip_runtime.h>

// Chamfer distance via bf16 split-MFMA.
//   d(p,q') = ||p||^2 + (||q'||^2 + 512 - 2 p.q') - 512
// Rank-15 GEMM in bf16 hi/lo-split form; one v_mfma_f32_32x32x16_bf16 =
// 32 targets x 32 queries = 1024 pairs; +512 bias keeps outputs positive so
// the fold runs as v_min3_u32 (uint order == float order for x >= 0).
//
// R13 ablation decode: top-5 = V2 (pure MFMA dep chain) at 22.8us/pass;
// V1 (independent MFMAs, no fold) ~17us/pass; real kernel 39-42us/pass.
// R12's VGPR_Count=28 cannot hold the >=48 live f32 (cz+dprev) in arch
// VGPRs -> allocator kept f32x16s in AGPRs and inserted accvgpr copies at
// every "v"-constrained asm boundary: the phantom VALU that survived
// R10-R12 (all schedules passed f32x16 across asm boundaries).
// R14: NO f32x16 crosses an asm boundary. One mega-block per MFMA with
// PHYSICAL registers: MFMA -> v[40:55] (clobbered, reused every block),
// literal-0 C (inline const legal in any src field), 24cy s_nop hazard pad,
// 8 v_min3_u32 fold in-block; only `best` (u32) crosses. ~60 VGPR total.

typedef __attribute__((ext_vector_type(8))) short  s16x8;
typedef __attribute__((ext_vector_type(16))) float f32x16;
typedef unsigned int u32;

#define TSLICE 512    // targets staged in LDS per block (16 KB packed)
#define QPB    512    // queries per block (4 waves x 128)
#define QPW    128    // queries per wave (4 frags of 32)

__device__ inline u32 umin3(u32 a, u32 b, u32 c) {
    const u32 t = a < b ? a : b;
    return t < c ? t : c;           // -> v_min3_u32
}

// Mega-block: MFMA into physical v[40:55] (C = inline 0), 24cy hazard pad,
// fold 16 -> best in 8 v_min3_u32 using physical temps v[56:60].
// D never leaves the block: no tuple crosses an asm boundary -> no AGPR
// shuttling. Same physical D regs reused by all blocks (in-order stream;
// WAR on issue-reads is safe; >=40cy between same-dst MFMAs).
__device__ inline void mfma_fold_phys(const s16x8 a, const s16x8 b, u32& best) {
    asm volatile(
        "v_mfma_f32_32x32x16_bf16 v[40:55], %1, %2, 0\n\t"
        "s_nop 7\n\t"
        "s_nop 7\n\t"
        "s_nop 7\n\t"
        "v_min3_u32 v56, v40, v41, v42\n\t"
        "v_min3_u32 v57, v43, v44, v45\n\t"
        "v_min3_u32 v58, v46, v47, v48\n\t"
        "v_min3_u32 v59, v49, v50, v51\n\t"
        "v_min3_u32 v60, v52, v53, v54\n\t"
        "v_min3_u32 v56, v56, v57, v55\n\t"
        "v_min3_u32 v58, v58, v59, v60\n\t"
        "v_min3_u32 %0, v56, v58, %0"
        : "+v"(best)
        : "v"(a), "v"(b)
        : "v40","v41","v42","v43","v44","v45","v46","v47",
          "v48","v49","v50","v51","v52","v53","v54","v55",
          "v56","v57","v58","v59","v60");
}

// ---------- bf16 split helper (bit-level, RNE) ----------
__device__ inline unsigned int bf16bits(float v, float &hival) {
    unsigned int u = __float_as_uint(v);
    unsigned int r = (u + 0x7FFFu + ((u >> 16) & 1u)) >> 16;
    hival = __uint_as_float(r << 16);
    return r;
}

// ---------- fused pre-pass: pack both inputs + sentinel-init d_out ----------
__global__ __launch_bounds__(256)
void pack_all_kernel(const float* __restrict__ in1, const float* __restrict__ in2,
                     ushort* __restrict__ A1, ushort* __restrict__ B1, float* __restrict__ S1,
                     ushort* __restrict__ A2, ushort* __restrict__ B2, float* __restrict__ S2,
                     unsigned int* __restrict__ out, int P1, int P2) {
    const int g = blockIdx.x * 256 + threadIdx.x;
    if (g >= P1 + P2) return;
    out[g] = 0x7F7F7F7Fu;                 // 3.39e38f sentinel (flat over both outs)

    const float* src; ushort* pA; ushort* pB; float* sq; int p;
    if (g < P1) { src = in1; pA = A1; pB = B1; sq = S1; p = g; }
    else        { src = in2; pA = A2; pB = B2; sq = S2; p = g - P1; }

    const float x = src[3*p+0], y = src[3*p+1], z = src[3*p+2];
    float xhf, xlf, yhf, ylf, zhf, zlf, shf, tmp;
    const ushort xh = (ushort)bf16bits(x, xhf);
    const ushort xl = (ushort)bf16bits(x - xhf, xlf);
    const ushort yh = (ushort)bf16bits(y, yhf);
    const ushort yl = (ushort)bf16bits(y - yhf, ylf);
    const ushort zh = (ushort)bf16bits(z, zhf);
    const ushort zl = (ushort)bf16bits(z - zhf, zlf);
    const float s = fmaf(x, x, fmaf(y, y, z * z));
    const ushort sh = (ushort)bf16bits(s, shf);
    const ushort sl = (ushort)bf16bits(s - shf, tmp);
    const ushort m2xh = (ushort)bf16bits(-2.0f * xhf, tmp);
    const ushort m2xl = (ushort)bf16bits(-2.0f * xlf, tmp);
    const ushort m2yh = (ushort)bf16bits(-2.0f * yhf, tmp);
    const ushort m2yl = (ushort)bf16bits(-2.0f * ylf, tmp);
    const ushort m2zh = (ushort)bf16bits(-2.0f * zhf, tmp);
    const ushort m2zl = (ushort)bf16bits(-2.0f * zlf, tmp);
    const ushort ONE  = 0x3F80;           // 1.0 bf16
    const ushort BIAS = 0x4400;           // 512.0 bf16 (exact)

    const s16x8 a0 = {(short)m2xh,(short)m2xl,(short)m2xh,(short)m2xl,
                      (short)m2yh,(short)m2yl,(short)m2yh,(short)m2yl};
    const s16x8 a1 = {(short)m2zh,(short)m2zl,(short)m2zh,(short)m2zl,
                      (short)sh,  (short)sl,  (short)BIAS, 0};
    const s16x8 b0 = {(short)xh,(short)xh,(short)xl,(short)xl,
                      (short)yh,(short)yh,(short)yl,(short)yl};
    const s16x8 b1 = {(short)zh,(short)zh,(short)zl,(short)zl,
                      (short)ONE,(short)ONE,(short)ONE, 0};

    s16x8* A8 = (s16x8*)pA;
    s16x8* B8 = (s16x8*)pB;
    // A: fragment-linear per 32-target tile: chunk = tilebase*64 + khalf*32 + row
    const int c0 = (p & ~31) * 2 + (p & 31);
    A8[c0]      = a0;   // k-slots 0-7  (lanes 0-31)
    A8[c0 + 32] = a1;   // k-slots 8-15 (lanes 32-63)
    // B: point-major
    B8[2*p]     = b0;
    B8[2*p + 1] = b1;
    sq[p] = s;
}

// ---------- main MFMA kernel, both directions (blockIdx.z selects) ----------
__global__ __launch_bounds__(256)
void chamfer_mfma_kernel(const ushort* __restrict__ Ad1, const ushort* __restrict__ Bd1,
                         const float*  __restrict__ Sd1, unsigned int* __restrict__ Od1,
                         const ushort* __restrict__ Ad2, const ushort* __restrict__ Bd2,
                         const float*  __restrict__ Sd2, unsigned int* __restrict__ Od2,
                         int Np, int Mp) {
    __shared__ s16x8 lds8[TSLICE * 2];   // 16 KB
    const int z = blockIdx.z;
    const ushort* pA  = z ? Ad2 : Ad1;
    const ushort* pB  = z ? Bd2 : Bd1;
    const float*  sqq = z ? Sd2 : Sd1;
    unsigned int* out = z ? Od2 : Od1;

    const int tid  = threadIdx.x;
    const int lane = tid & 63;
    const int wid  = tid >> 6;
    const int qblock = blockIdx.x * QPB;        // flat over B*Np (QPB | Np)
    const int b = qblock / Np;
    const size_t gchunk = ((size_t)b * Mp + (size_t)blockIdx.y * TSLICE) * 2;
    const s16x8* gA = (const s16x8*)pA + gchunk;
    for (int i = tid; i < TSLICE * 2; i += 256) lds8[i] = gA[i];

    // B fragments: 4 x 32 queries, loop-invariant in registers
    const int qw = qblock + wid * QPW;
    s16x8 bfr0, bfr1, bfr2, bfr3;
    {
        const int qb = qw + (lane & 31);
        const size_t hi = (size_t)(lane >> 5) * 8;
        bfr0 = *(const s16x8*)(pB + (size_t)(qb +  0) * 16 + hi);
        bfr1 = *(const s16x8*)(pB + (size_t)(qb + 32) * 16 + hi);
        bfr2 = *(const s16x8*)(pB + (size_t)(qb + 64) * 16 + hi);
        bfr3 = *(const s16x8*)(pB + (size_t)(qb + 96) * 16 + hi);
    }
    __syncthreads();

    u32 b0 = 0x7F7F7F7Fu, b1 = 0x7F7F7F7Fu, b2 = 0x7F7F7F7Fu, b3 = 0x7F7F7F7Fu;

    const int NT = TSLICE / 32;
    s16x8 a = lds8[lane];
    for (int t = 0; t < NT; ++t) {
        const int tn = (t + 1 < NT) ? (t + 1) : t;
        const s16x8 an = lds8[tn * 64 + lane];   // prefetch next A fragment
        mfma_fold_phys(a, bfr0, b0);
        mfma_fold_phys(a, bfr1, b1);
        mfma_fold_phys(a, bfr2, b2);
        mfma_fold_phys(a, bfr3, b3);
        a = an;
    }

    u32 bests[4] = {b0, b1, b2, b3};
    #pragma unroll
    for (int f = 0; f < 4; ++f) {
        u32 bu = bests[f];
        const u32 other = __shfl_xor(bu, 32);                 // merge row halves
        bu = bu < other ? bu : other;
        const int q = qw + f * 32 + (lane & 31);
        float v = (__uint_as_float(bu) - 512.0f) + sqq[q];    // un-bias
        v = fmaxf(v, 0.0f);                                   // clamp: keep >= 0
        if (lane < 32) atomicMin(out + q, __float_as_uint(v));
    }
}

// ---------- fallback (round-2 VALU kernel) if ws too small ----------
#define FSLICE 512
#define FROWS  512
__global__ __launch_bounds__(256)
void chamfer_dir_kernel(const float* __restrict__ P, const float* __restrict__ Q,
                        unsigned int* __restrict__ out, int Np, int Mp) {
    __shared__ float4 lds[FSLICE];
    const int tid = threadIdx.x;
    const int rowBase = blockIdx.x * FROWS;
    const int b = rowBase / Np;
    const int slice0 = blockIdx.y * FSLICE;
    const float* qs = Q + ((size_t)b * Mp + slice0) * 3;
    #pragma unroll
    for (int i = tid; i < FSLICE; i += 256) {
        const float x = qs[3*i+0], y = qs[3*i+1], z = qs[3*i+2];
        lds[i] = make_float4(x, y, z, fmaf(x, x, fmaf(y, y, z * z)));
    }
    const int q0 = rowBase + tid, q1 = q0 + 256;
    const float* p0 = P + (size_t)q0 * 3;
    const float* p1 = P + (size_t)q1 * 3;
    const float x0=p0[0], y0=p0[1], z0=p0[2], x1=p1[0], y1=p1[1], z1=p1[2];
    const float m2x0=-2*x0, m2y0=-2*y0, m2z0=-2*z0, m2x1=-2*x1, m2y1=-2*y1, m2z1=-2*z1;
    const float sqp0 = fmaf(x0,x0,fmaf(y0,y0,z0*z0));
    const float sqp1 = fmaf(x1,x1,fmaf(y1,y1,z1*z1));
    __syncthreads();
    float best0 = 3.0e38f, best1 = 3.0e38f;
    #pragma unroll 4
    for (int j = 0; j < FSLICE; j += 2) {
        const float4 a = lds[j], c = lds[j+1];
        const float d00 = fmaf(m2x0,a.x,fmaf(m2y0,a.y,fmaf(m2z0,a.z,a.w)));
        const float d01 = fmaf(m2x0,c.x,fmaf(m2y0,c.y,fmaf(m2z0,c.z,c.w)));
        best0 = fminf(fminf(d00,d01), best0);
        const float d10 = fmaf(m2x1,a.x,fmaf(m2y1,a.y,fmaf(m2z1,a.z,a.w)));
        const float d11 = fmaf(m2x1,c.x,fmaf(m2y1,c.y,fmaf(m2z1,c.z,c.w)));
        best1 = fminf(fminf(d10,d11), best1);
    }
    atomicMin(out + q0, __float_as_uint(fmaxf(best0 + sqp0, 0.f)));
    atomicMin(out + q1, __float_as_uint(fmaxf(best1 + sqp1, 0.f)));
}

extern "C" void kernel_launch(void* const* d_in, const int* in_sizes, int n_in,
                              void* d_out, int out_size, void* d_ws, size_t ws_size,
                              hipStream_t stream) {
    const float* in1 = (const float*)d_in[0];   // [B, N, 3]
    const float* in2 = (const float*)d_in[1];   // [B, M, 3]
    const int B = 8;
    const int N = in_sizes[0] / (B * 3);
    const int M = in_sizes[1] / (B * 3);
    const int P1 = B * N, P2 = B * M;
    unsigned int* out = (unsigned int*)d_out;

    const size_t packBytes1 = (size_t)P1 * 32, packBytes2 = (size_t)P2 * 32;
    const size_t need = 2*packBytes1 + 2*packBytes2 + (size_t)(P1+P2)*4;

    if (ws_size >= need && N == M) {
        char* w = (char*)d_ws;
        ushort* A1 = (ushort*)(w);
        ushort* B1 = (ushort*)(w + packBytes1);
        ushort* A2 = (ushort*)(w + 2*packBytes1);
        ushort* B2 = (ushort*)(w + 2*packBytes1 + packBytes2);
        float*  S1 = (float*) (w + 2*packBytes1 + 2*packBytes2);
        float*  S2 = (float*) (w + 2*packBytes1 + 2*packBytes2 + (size_t)P1*4);

        pack_all_kernel<<<(P1 + P2 + 255)/256, 256, 0, stream>>>(
            in1, in2, A1, B1, S1, A2, B2, S2, out, P1, P2);

        // z=0: dist1 (queries=input1, targets=input2); z=1: dist2
        dim3 g(P1 / QPB, M / TSLICE, 2);
        chamfer_mfma_kernel<<<g, 256, 0, stream>>>(
            A2, B1, S1, out,        // dir 1
            A1, B2, S2, out + P1,   // dir 2
            N, M);
    } else {
        hipMemsetAsync(d_out, 0x7F, (size_t)out_size * sizeof(float), stream);
        dim3 g1(P1 / FROWS, M / FSLICE);
        chamfer_dir_kernel<<<g1, 256, 0, stream>>>(in1, in2, out, N, M);
        dim3 g2(P2 / FROWS, N / FSLICE);
        chamfer_dir_kernel<<<g2, 256, 0, stream>>>(in2, in1, out + P1, M, N);
    }
}

// Round 15
// 46.332 us; speedup vs baseline: 5.2870x; 1.0055x over previous
//
#include <hip/hip_runtime.h>

// Chamfer distance via bf16 split-MFMA.
//   d(p,q') = ||p||^2 + (||q'||^2 + 512 - 2 p.q') - 512
// Rank-15 GEMM in bf16 hi/lo-split form; one v_mfma_f32_32x32x16_bf16 =
// 32 targets x 32 queries = 1024 pairs; +512 bias keeps outputs positive so
// the fold runs as v_min3_u32 (uint order == float order for x >= 0).
//
// R13/R14 ablation: V1 (MFMA + 1 min3) ~17us/pass = pipe ceiling; the full
// 8-min3 fold with s_nop walls costs +22us/pass -- the per-wave serial
// chain (MFMA -> 24cy nops -> fold) becomes the SIMD rate. R15 deletes the
// chain: 4 physical D tuples (one per frag); each asm block folds tuple f's
// PREVIOUS value (written at t-1, ~60cy ago -> no nops needed) then issues
// MFMA(t,f) into it. WAR within the block is safe in-order. Per-wave cost
// ~20cy/block < 32cy MFMA pipe period -> matrix-bound even at 1 wave/SIMD.

typedef __attribute__((ext_vector_type(8))) short  s16x8;
typedef __attribute__((ext_vector_type(16))) float f32x16;
typedef unsigned int u32;

#define TSLICE 512    // targets staged in LDS per block (16 KB packed)
#define QPB    512    // queries per block (4 waves x 128)
#define QPW    128    // queries per wave (4 frags of 32)

__device__ inline u32 umin3(u32 a, u32 b, u32 c) {
    const u32 t = a < b ? a : b;
    return t < c ? t : c;           // -> v_min3_u32
}

// fold(tuple at t-1) -> best, then MFMA(t) into the same tuple.
// Tuples: f0=v[48:63] f1=v[64:79] f2=v[80:95] f3=v[96:111]; temps v112-116.
#define STEP_ASM(B0,B1,B2,B3,B4,B5,B6,B7,B8,B9,B10,B11,B12,B13,B14,B15,RANGE) \
    asm volatile( \
        "v_min3_u32 v112, v" #B0 ", v" #B1 ", v" #B2 "\n\t" \
        "v_min3_u32 v113, v" #B3 ", v" #B4 ", v" #B5 "\n\t" \
        "v_min3_u32 v114, v" #B6 ", v" #B7 ", v" #B8 "\n\t" \
        "v_min3_u32 v115, v" #B9 ", v" #B10 ", v" #B11 "\n\t" \
        "v_min3_u32 v116, v" #B12 ", v" #B13 ", v" #B14 "\n\t" \
        "v_min3_u32 v112, v112, v113, v" #B15 "\n\t" \
        "v_min3_u32 v114, v114, v115, v116\n\t" \
        "v_min3_u32 %0, v112, v114, %0\n\t" \
        "v_mfma_f32_32x32x16_bf16 " RANGE ", %1, %2, 0" \
        : "+v"(best) : "v"(a), "v"(b) \
        : "v" #B0, "v" #B1, "v" #B2, "v" #B3, "v" #B4, "v" #B5, "v" #B6, \
          "v" #B7, "v" #B8, "v" #B9, "v" #B10, "v" #B11, "v" #B12, \
          "v" #B13, "v" #B14, "v" #B15, "v112","v113","v114","v115","v116")

__device__ inline void step_f0(const s16x8 a, const s16x8 b, u32& best) {
    STEP_ASM(48,49,50,51,52,53,54,55,56,57,58,59,60,61,62,63, "v[48:63]");
}
__device__ inline void step_f1(const s16x8 a, const s16x8 b, u32& best) {
    STEP_ASM(64,65,66,67,68,69,70,71,72,73,74,75,76,77,78,79, "v[64:79]");
}
__device__ inline void step_f2(const s16x8 a, const s16x8 b, u32& best) {
    STEP_ASM(80,81,82,83,84,85,86,87,88,89,90,91,92,93,94,95, "v[80:95]");
}
__device__ inline void step_f3(const s16x8 a, const s16x8 b, u32& best) {
    STEP_ASM(96,97,98,99,100,101,102,103,104,105,106,107,108,109,110,111, "v[96:111]");
}

// Epilogue fold-only (no MFMA) of one tuple.
#define FOLD_ASM(B0,B1,B2,B3,B4,B5,B6,B7,B8,B9,B10,B11,B12,B13,B14,B15) \
    asm volatile( \
        "v_min3_u32 v112, v" #B0 ", v" #B1 ", v" #B2 "\n\t" \
        "v_min3_u32 v113, v" #B3 ", v" #B4 ", v" #B5 "\n\t" \
        "v_min3_u32 v114, v" #B6 ", v" #B7 ", v" #B8 "\n\t" \
        "v_min3_u32 v115, v" #B9 ", v" #B10 ", v" #B11 "\n\t" \
        "v_min3_u32 v116, v" #B12 ", v" #B13 ", v" #B14 "\n\t" \
        "v_min3_u32 v112, v112, v113, v" #B15 "\n\t" \
        "v_min3_u32 v114, v114, v115, v116\n\t" \
        "v_min3_u32 %0, v112, v114, %0" \
        : "+v"(best) :: "v112","v113","v114","v115","v116")

__device__ inline void fold_f0(u32& best) { FOLD_ASM(48,49,50,51,52,53,54,55,56,57,58,59,60,61,62,63); }
__device__ inline void fold_f1(u32& best) { FOLD_ASM(64,65,66,67,68,69,70,71,72,73,74,75,76,77,78,79); }
__device__ inline void fold_f2(u32& best) { FOLD_ASM(80,81,82,83,84,85,86,87,88,89,90,91,92,93,94,95); }
__device__ inline void fold_f3(u32& best) { FOLD_ASM(96,97,98,99,100,101,102,103,104,105,106,107,108,109,110,111); }

// ---------- bf16 split helper (bit-level, RNE) ----------
__device__ inline unsigned int bf16bits(float v, float &hival) {
    unsigned int u = __float_as_uint(v);
    unsigned int r = (u + 0x7FFFu + ((u >> 16) & 1u)) >> 16;
    hival = __uint_as_float(r << 16);
    return r;
}

// ---------- fused pre-pass: pack both inputs + sentinel-init d_out ----------
__global__ __launch_bounds__(256)
void pack_all_kernel(const float* __restrict__ in1, const float* __restrict__ in2,
                     ushort* __restrict__ A1, ushort* __restrict__ B1, float* __restrict__ S1,
                     ushort* __restrict__ A2, ushort* __restrict__ B2, float* __restrict__ S2,
                     unsigned int* __restrict__ out, int P1, int P2) {
    const int g = blockIdx.x * 256 + threadIdx.x;
    if (g >= P1 + P2) return;
    out[g] = 0x7F7F7F7Fu;                 // 3.39e38f sentinel (flat over both outs)

    const float* src; ushort* pA; ushort* pB; float* sq; int p;
    if (g < P1) { src = in1; pA = A1; pB = B1; sq = S1; p = g; }
    else        { src = in2; pA = A2; pB = B2; sq = S2; p = g - P1; }

    const float x = src[3*p+0], y = src[3*p+1], z = src[3*p+2];
    float xhf, xlf, yhf, ylf, zhf, zlf, shf, tmp;
    const ushort xh = (ushort)bf16bits(x, xhf);
    const ushort xl = (ushort)bf16bits(x - xhf, xlf);
    const ushort yh = (ushort)bf16bits(y, yhf);
    const ushort yl = (ushort)bf16bits(y - yhf, ylf);
    const ushort zh = (ushort)bf16bits(z, zhf);
    const ushort zl = (ushort)bf16bits(z - zhf, zlf);
    const float s = fmaf(x, x, fmaf(y, y, z * z));
    const ushort sh = (ushort)bf16bits(s, shf);
    const ushort sl = (ushort)bf16bits(s - shf, tmp);
    const ushort m2xh = (ushort)bf16bits(-2.0f * xhf, tmp);
    const ushort m2xl = (ushort)bf16bits(-2.0f * xlf, tmp);
    const ushort m2yh = (ushort)bf16bits(-2.0f * yhf, tmp);
    const ushort m2yl = (ushort)bf16bits(-2.0f * ylf, tmp);
    const ushort m2zh = (ushort)bf16bits(-2.0f * zhf, tmp);
    const ushort m2zl = (ushort)bf16bits(-2.0f * zlf, tmp);
    const ushort ONE  = 0x3F80;           // 1.0 bf16
    const ushort BIAS = 0x4400;           // 512.0 bf16 (exact)

    const s16x8 a0 = {(short)m2xh,(short)m2xl,(short)m2xh,(short)m2xl,
                      (short)m2yh,(short)m2yl,(short)m2yh,(short)m2yl};
    const s16x8 a1 = {(short)m2zh,(short)m2zl,(short)m2zh,(short)m2zl,
                      (short)sh,  (short)sl,  (short)BIAS, 0};
    const s16x8 b0 = {(short)xh,(short)xh,(short)xl,(short)xl,
                      (short)yh,(short)yh,(short)yl,(short)yl};
    const s16x8 b1 = {(short)zh,(short)zh,(short)zl,(short)zl,
                      (short)ONE,(short)ONE,(short)ONE, 0};

    s16x8* A8 = (s16x8*)pA;
    s16x8* B8 = (s16x8*)pB;
    // A: fragment-linear per 32-target tile: chunk = tilebase*64 + khalf*32 + row
    const int c0 = (p & ~31) * 2 + (p & 31);
    A8[c0]      = a0;   // k-slots 0-7  (lanes 0-31)
    A8[c0 + 32] = a1;   // k-slots 8-15 (lanes 32-63)
    // B: point-major
    B8[2*p]     = b0;
    B8[2*p + 1] = b1;
    sq[p] = s;
}

// ---------- main MFMA kernel, both directions (blockIdx.z selects) ----------
__global__ __launch_bounds__(256)
void chamfer_mfma_kernel(const ushort* __restrict__ Ad1, const ushort* __restrict__ Bd1,
                         const float*  __restrict__ Sd1, unsigned int* __restrict__ Od1,
                         const ushort* __restrict__ Ad2, const ushort* __restrict__ Bd2,
                         const float*  __restrict__ Sd2, unsigned int* __restrict__ Od2,
                         int Np, int Mp) {
    __shared__ s16x8 lds8[TSLICE * 2];   // 16 KB
    const int z = blockIdx.z;
    const ushort* pA  = z ? Ad2 : Ad1;
    const ushort* pB  = z ? Bd2 : Bd1;
    const float*  sqq = z ? Sd2 : Sd1;
    unsigned int* out = z ? Od2 : Od1;

    const int tid  = threadIdx.x;
    const int lane = tid & 63;
    const int wid  = tid >> 6;
    const int qblock = blockIdx.x * QPB;        // flat over B*Np (QPB | Np)
    const int b = qblock / Np;
    const size_t gchunk = ((size_t)b * Mp + (size_t)blockIdx.y * TSLICE) * 2;
    const s16x8* gA = (const s16x8*)pA + gchunk;
    for (int i = tid; i < TSLICE * 2; i += 256) lds8[i] = gA[i];

    // B fragments: 4 x 32 queries, loop-invariant in registers
    const int qw = qblock + wid * QPW;
    s16x8 bfr0, bfr1, bfr2, bfr3;
    {
        const int qb = qw + (lane & 31);
        const size_t hi = (size_t)(lane >> 5) * 8;
        bfr0 = *(const s16x8*)(pB + (size_t)(qb +  0) * 16 + hi);
        bfr1 = *(const s16x8*)(pB + (size_t)(qb + 32) * 16 + hi);
        bfr2 = *(const s16x8*)(pB + (size_t)(qb + 64) * 16 + hi);
        bfr3 = *(const s16x8*)(pB + (size_t)(qb + 96) * 16 + hi);
    }
    __syncthreads();

    // Sentinel-init the 4 physical D tuples (their first fold is harmless).
    asm volatile(
        "v_mov_b32 v48, 0x7f7f7f7f\n\tv_mov_b32 v49, 0x7f7f7f7f\n\t"
        "v_mov_b32 v50, 0x7f7f7f7f\n\tv_mov_b32 v51, 0x7f7f7f7f\n\t"
        "v_mov_b32 v52, 0x7f7f7f7f\n\tv_mov_b32 v53, 0x7f7f7f7f\n\t"
        "v_mov_b32 v54, 0x7f7f7f7f\n\tv_mov_b32 v55, 0x7f7f7f7f\n\t"
        "v_mov_b32 v56, 0x7f7f7f7f\n\tv_mov_b32 v57, 0x7f7f7f7f\n\t"
        "v_mov_b32 v58, 0x7f7f7f7f\n\tv_mov_b32 v59, 0x7f7f7f7f\n\t"
        "v_mov_b32 v60, 0x7f7f7f7f\n\tv_mov_b32 v61, 0x7f7f7f7f\n\t"
        "v_mov_b32 v62, 0x7f7f7f7f\n\tv_mov_b32 v63, 0x7f7f7f7f\n\t"
        "v_mov_b32 v64, 0x7f7f7f7f\n\tv_mov_b32 v65, 0x7f7f7f7f\n\t"
        "v_mov_b32 v66, 0x7f7f7f7f\n\tv_mov_b32 v67, 0x7f7f7f7f\n\t"
        "v_mov_b32 v68, 0x7f7f7f7f\n\tv_mov_b32 v69, 0x7f7f7f7f\n\t"
        "v_mov_b32 v70, 0x7f7f7f7f\n\tv_mov_b32 v71, 0x7f7f7f7f\n\t"
        "v_mov_b32 v72, 0x7f7f7f7f\n\tv_mov_b32 v73, 0x7f7f7f7f\n\t"
        "v_mov_b32 v74, 0x7f7f7f7f\n\tv_mov_b32 v75, 0x7f7f7f7f\n\t"
        "v_mov_b32 v76, 0x7f7f7f7f\n\tv_mov_b32 v77, 0x7f7f7f7f\n\t"
        "v_mov_b32 v78, 0x7f7f7f7f\n\tv_mov_b32 v79, 0x7f7f7f7f\n\t"
        "v_mov_b32 v80, 0x7f7f7f7f\n\tv_mov_b32 v81, 0x7f7f7f7f\n\t"
        "v_mov_b32 v82, 0x7f7f7f7f\n\tv_mov_b32 v83, 0x7f7f7f7f\n\t"
        "v_mov_b32 v84, 0x7f7f7f7f\n\tv_mov_b32 v85, 0x7f7f7f7f\n\t"
        "v_mov_b32 v86, 0x7f7f7f7f\n\tv_mov_b32 v87, 0x7f7f7f7f\n\t"
        "v_mov_b32 v88, 0x7f7f7f7f\n\tv_mov_b32 v89, 0x7f7f7f7f\n\t"
        "v_mov_b32 v90, 0x7f7f7f7f\n\tv_mov_b32 v91, 0x7f7f7f7f\n\t"
        "v_mov_b32 v92, 0x7f7f7f7f\n\tv_mov_b32 v93, 0x7f7f7f7f\n\t"
        "v_mov_b32 v94, 0x7f7f7f7f\n\tv_mov_b32 v95, 0x7f7f7f7f\n\t"
        "v_mov_b32 v96, 0x7f7f7f7f\n\tv_mov_b32 v97, 0x7f7f7f7f\n\t"
        "v_mov_b32 v98, 0x7f7f7f7f\n\tv_mov_b32 v99, 0x7f7f7f7f\n\t"
        "v_mov_b32 v100, 0x7f7f7f7f\n\tv_mov_b32 v101, 0x7f7f7f7f\n\t"
        "v_mov_b32 v102, 0x7f7f7f7f\n\tv_mov_b32 v103, 0x7f7f7f7f\n\t"
        "v_mov_b32 v104, 0x7f7f7f7f\n\tv_mov_b32 v105, 0x7f7f7f7f\n\t"
        "v_mov_b32 v106, 0x7f7f7f7f\n\tv_mov_b32 v107, 0x7f7f7f7f\n\t"
        "v_mov_b32 v108, 0x7f7f7f7f\n\tv_mov_b32 v109, 0x7f7f7f7f\n\t"
        "v_mov_b32 v110, 0x7f7f7f7f\n\tv_mov_b32 v111, 0x7f7f7f7f"
        ::: "v48","v49","v50","v51","v52","v53","v54","v55",
            "v56","v57","v58","v59","v60","v61","v62","v63",
            "v64","v65","v66","v67","v68","v69","v70","v71",
            "v72","v73","v74","v75","v76","v77","v78","v79",
            "v80","v81","v82","v83","v84","v85","v86","v87",
            "v88","v89","v90","v91","v92","v93","v94","v95",
            "v96","v97","v98","v99","v100","v101","v102","v103",
            "v104","v105","v106","v107","v108","v109","v110","v111");

    u32 b0 = 0x7F7F7F7Fu, b1 = 0x7F7F7F7Fu, b2 = 0x7F7F7F7Fu, b3 = 0x7F7F7F7Fu;

    const int NT = TSLICE / 32;
    s16x8 a = lds8[lane];
    for (int t = 0; t < NT; ++t) {
        const int tn = (t + 1 < NT) ? (t + 1) : t;
        const s16x8 an = lds8[tn * 64 + lane];   // prefetch next A fragment
        step_f0(a, bfr0, b0);   // fold D(t-1,f0) then MFMA(t,f0)
        step_f1(a, bfr1, b1);
        step_f2(a, bfr2, b2);
        step_f3(a, bfr3, b3);
        a = an;
    }

    // One-time hazard guard, then fold the last iteration's 4 tuples.
    asm volatile("s_nop 7\n\ts_nop 7\n\ts_nop 7");
    fold_f0(b0); fold_f1(b1); fold_f2(b2); fold_f3(b3);

    u32 bests[4] = {b0, b1, b2, b3};
    #pragma unroll
    for (int f = 0; f < 4; ++f) {
        u32 bu = bests[f];
        const u32 other = __shfl_xor(bu, 32);                 // merge row halves
        bu = bu < other ? bu : other;
        const int q = qw + f * 32 + (lane & 31);
        float v = (__uint_as_float(bu) - 512.0f) + sqq[q];    // un-bias
        v = fmaxf(v, 0.0f);                                   // clamp: keep >= 0
        if (lane < 32) atomicMin(out + q, __float_as_uint(v));
    }
}

// ---------- fallback (round-2 VALU kernel) if ws too small ----------
#define FSLICE 512
#define FROWS  512
__global__ __launch_bounds__(256)
void chamfer_dir_kernel(const float* __restrict__ P, const float* __restrict__ Q,
                        unsigned int* __restrict__ out, int Np, int Mp) {
    __shared__ float4 lds[FSLICE];
    const int tid = threadIdx.x;
    const int rowBase = blockIdx.x * FROWS;
    const int b = rowBase / Np;
    const int slice0 = blockIdx.y * FSLICE;
    const float* qs = Q + ((size_t)b * Mp + slice0) * 3;
    #pragma unroll
    for (int i = tid; i < FSLICE; i += 256) {
        const float x = qs[3*i+0], y = qs[3*i+1], z = qs[3*i+2];
        lds[i] = make_float4(x, y, z, fmaf(x, x, fmaf(y, y, z * z)));
    }
    const int q0 = rowBase + tid, q1 = q0 + 256;
    const float* p0 = P + (size_t)q0 * 3;
    const float* p1 = P + (size_t)q1 * 3;
    const float x0=p0[0], y0=p0[1], z0=p0[2], x1=p1[0], y1=p1[1], z1=p1[2];
    const float m2x0=-2*x0, m2y0=-2*y0, m2z0=-2*z0, m2x1=-2*x1, m2y1=-2*y1, m2z1=-2*z1;
    const float sqp0 = fmaf(x0,x0,fmaf(y0,y0,z0*z0));
    const float sqp1 = fmaf(x1,x1,fmaf(y1,y1,z1*z1));
    __syncthreads();
    float best0 = 3.0e38f, best1 = 3.0e38f;
    #pragma unroll 4
    for (int j = 0; j < FSLICE; j += 2) {
        const float4 a = lds[j], c = lds[j+1];
        const float d00 = fmaf(m2x0,a.x,fmaf(m2y0,a.y,fmaf(m2z0,a.z,a.w)));
        const float d01 = fmaf(m2x0,c.x,fmaf(m2y0,c.y,fmaf(m2z0,c.z,c.w)));
        best0 = fminf(fminf(d00,d01), best0);
        const float d10 = fmaf(m2x1,a.x,fmaf(m2y1,a.y,fmaf(m2z1,a.z,a.w)));
        const float d11 = fmaf(m2x1,c.x,fmaf(m2y1,c.y,fmaf(m2z1,c.z,c.w)));
        best1 = fminf(fminf(d10,d11), best1);
    }
    atomicMin(out + q0, __float_as_uint(fmaxf(best0 + sqp0, 0.f)));
    atomicMin(out + q1, __float_as_uint(fmaxf(best1 + sqp1, 0.f)));
}

extern "C" void kernel_launch(void* const* d_in, const int* in_sizes, int n_in,
                              void* d_out, int out_size, void* d_ws, size_t ws_size,
                              hipStream_t stream) {
    const float* in1 = (const float*)d_in[0];   // [B, N, 3]
    const float* in2 = (const float*)d_in[1];   // [B, M, 3]
    const int B = 8;
    const int N = in_sizes[0] / (B * 3);
    const int M = in_sizes[1] / (B * 3);
    const int P1 = B * N, P2 = B * M;
    unsigned int* out = (unsigned int*)d_out;

    const size_t packBytes1 = (size_t)P1 * 32, packBytes2 = (size_t)P2 * 32;
    const size_t need = 2*packBytes1 + 2*packBytes2 + (size_t)(P1+P2)*4;

    if (ws_size >= need && N == M) {
        char* w = (char*)d_ws;
        ushort* A1 = (ushort*)(w);
        ushort* B1 = (ushort*)(w + packBytes1);
        ushort* A2 = (ushort*)(w + 2*packBytes1);
        ushort* B2 = (ushort*)(w + 2*packBytes1 + packBytes2);
        float*  S1 = (float*) (w + 2*packBytes1 + 2*packBytes2);
        float*  S2 = (float*) (w + 2*packBytes1 + 2*packBytes2 + (size_t)P1*4);

        pack_all_kernel<<<(P1 + P2 + 255)/256, 256, 0, stream>>>(
            in1, in2, A1, B1, S1, A2, B2, S2, out, P1, P2);

        // z=0: dist1 (queries=input1, targets=input2); z=1: dist2
        dim3 g(P1 / QPB, M / TSLICE, 2);
        chamfer_mfma_kernel<<<g, 256, 0, stream>>>(
            A2, B1, S1, out,        // dir 1
            A1, B2, S2, out + P1,   // dir 2
            N, M);
    } else {
        hipMemsetAsync(d_out, 0x7F, (size_t)out_size * sizeof(float), stream);
        dim3 g1(P1 / FROWS, M / FSLICE);
        chamfer_dir_kernel<<<g1, 256, 0, stream>>>(in1, in2, out, N, M);
        dim3 g2(P2 / FROWS, N / FSLICE);
        chamfer_dir_kernel<<<g2, 256, 0, stream>>>(in2, in1, out + P1, M, N);
    }
}

// Round 16
// 46.307 us; speedup vs baseline: 5.2899x; 1.0005x over previous
//
#include <hip/hip_runtime.h>

// Chamfer distance via bf16 split-MFMA.
//   d(p,q') = ||p||^2 + (||q'||^2 + 512 - 2 p.q') - 512
// Rank-15 GEMM in bf16 hi/lo-split form; one v_mfma_f32_32x32x16_bf16 =
// 32 targets x 32 queries = 1024 pairs; +512 bias keeps outputs positive so
// the fold runs as v_min3_u32 (uint order == float order for x >= 0).
//
// Structure (converged over R5-R15):
//  - 4 physical D tuples (one per query-frag); each asm block folds the
//    tuple's PREVIOUS value (8 v_min3_u32, ~60cy after its MFMA -> no nops)
//    then issues MFMA(t,f) into it. Per-wave ~20cy/block.
//  - R13 ablation: fold tax is ~3.7cy per D-element READ (7 extra min3 =
//    +22us/pass across 5 schedule variants) -- irreducible: every D element
//    is a distinct pair that must enter a min. 8 min3/MFMA is the floor.
//  - R16: A-panel (2MB/dir) is L2-resident -> LDS staging was pure overhead
//    (Common-mistake #7). Direct global s16x8 reads, one-tile register
//    prefetch, NO __shared__, NO barrier anywhere in the kernel.

typedef __attribute__((ext_vector_type(8))) short  s16x8;
typedef unsigned int u32;

#define TSLICE 512    // targets per block (A chunk = 16 KB, L2-hot)
#define QPB    512    // queries per block (4 waves x 128)
#define QPW    128    // queries per wave (4 frags of 32)

__device__ inline u32 umin3(u32 a, u32 b, u32 c) {
    const u32 t = a < b ? a : b;
    return t < c ? t : c;           // -> v_min3_u32
}

// fold(tuple at t-1) -> best, then MFMA(t) into the same tuple.
// Tuples: f0=v[48:63] f1=v[64:79] f2=v[80:95] f3=v[96:111]; temps v112-116.
#define STEP_ASM(B0,B1,B2,B3,B4,B5,B6,B7,B8,B9,B10,B11,B12,B13,B14,B15,RANGE) \
    asm volatile( \
        "v_min3_u32 v112, v" #B0 ", v" #B1 ", v" #B2 "\n\t" \
        "v_min3_u32 v113, v" #B3 ", v" #B4 ", v" #B5 "\n\t" \
        "v_min3_u32 v114, v" #B6 ", v" #B7 ", v" #B8 "\n\t" \
        "v_min3_u32 v115, v" #B9 ", v" #B10 ", v" #B11 "\n\t" \
        "v_min3_u32 v116, v" #B12 ", v" #B13 ", v" #B14 "\n\t" \
        "v_min3_u32 v112, v112, v113, v" #B15 "\n\t" \
        "v_min3_u32 v114, v114, v115, v116\n\t" \
        "v_min3_u32 %0, v112, v114, %0\n\t" \
        "v_mfma_f32_32x32x16_bf16 " RANGE ", %1, %2, 0" \
        : "+v"(best) : "v"(a), "v"(b) \
        : "v" #B0, "v" #B1, "v" #B2, "v" #B3, "v" #B4, "v" #B5, "v" #B6, \
          "v" #B7, "v" #B8, "v" #B9, "v" #B10, "v" #B11, "v" #B12, \
          "v" #B13, "v" #B14, "v" #B15, "v112","v113","v114","v115","v116")

__device__ inline void step_f0(const s16x8 a, const s16x8 b, u32& best) {
    STEP_ASM(48,49,50,51,52,53,54,55,56,57,58,59,60,61,62,63, "v[48:63]");
}
__device__ inline void step_f1(const s16x8 a, const s16x8 b, u32& best) {
    STEP_ASM(64,65,66,67,68,69,70,71,72,73,74,75,76,77,78,79, "v[64:79]");
}
__device__ inline void step_f2(const s16x8 a, const s16x8 b, u32& best) {
    STEP_ASM(80,81,82,83,84,85,86,87,88,89,90,91,92,93,94,95, "v[80:95]");
}
__device__ inline void step_f3(const s16x8 a, const s16x8 b, u32& best) {
    STEP_ASM(96,97,98,99,100,101,102,103,104,105,106,107,108,109,110,111, "v[96:111]");
}

// Epilogue fold-only (no MFMA) of one tuple.
#define FOLD_ASM(B0,B1,B2,B3,B4,B5,B6,B7,B8,B9,B10,B11,B12,B13,B14,B15) \
    asm volatile( \
        "v_min3_u32 v112, v" #B0 ", v" #B1 ", v" #B2 "\n\t" \
        "v_min3_u32 v113, v" #B3 ", v" #B4 ", v" #B5 "\n\t" \
        "v_min3_u32 v114, v" #B6 ", v" #B7 ", v" #B8 "\n\t" \
        "v_min3_u32 v115, v" #B9 ", v" #B10 ", v" #B11 "\n\t" \
        "v_min3_u32 v116, v" #B12 ", v" #B13 ", v" #B14 "\n\t" \
        "v_min3_u32 v112, v112, v113, v" #B15 "\n\t" \
        "v_min3_u32 v114, v114, v115, v116\n\t" \
        "v_min3_u32 %0, v112, v114, %0" \
        : "+v"(best) :: "v112","v113","v114","v115","v116")

__device__ inline void fold_f0(u32& best) { FOLD_ASM(48,49,50,51,52,53,54,55,56,57,58,59,60,61,62,63); }
__device__ inline void fold_f1(u32& best) { FOLD_ASM(64,65,66,67,68,69,70,71,72,73,74,75,76,77,78,79); }
__device__ inline void fold_f2(u32& best) { FOLD_ASM(80,81,82,83,84,85,86,87,88,89,90,91,92,93,94,95); }
__device__ inline void fold_f3(u32& best) { FOLD_ASM(96,97,98,99,100,101,102,103,104,105,106,107,108,109,110,111); }

// ---------- bf16 split helper (bit-level, RNE) ----------
__device__ inline unsigned int bf16bits(float v, float &hival) {
    unsigned int u = __float_as_uint(v);
    unsigned int r = (u + 0x7FFFu + ((u >> 16) & 1u)) >> 16;
    hival = __uint_as_float(r << 16);
    return r;
}

// ---------- fused pre-pass: pack both inputs + sentinel-init d_out ----------
__global__ __launch_bounds__(256)
void pack_all_kernel(const float* __restrict__ in1, const float* __restrict__ in2,
                     ushort* __restrict__ A1, ushort* __restrict__ B1, float* __restrict__ S1,
                     ushort* __restrict__ A2, ushort* __restrict__ B2, float* __restrict__ S2,
                     unsigned int* __restrict__ out, int P1, int P2) {
    const int g = blockIdx.x * 256 + threadIdx.x;
    if (g >= P1 + P2) return;
    out[g] = 0x7F7F7F7Fu;                 // 3.39e38f sentinel (flat over both outs)

    const float* src; ushort* pA; ushort* pB; float* sq; int p;
    if (g < P1) { src = in1; pA = A1; pB = B1; sq = S1; p = g; }
    else        { src = in2; pA = A2; pB = B2; sq = S2; p = g - P1; }

    const float x = src[3*p+0], y = src[3*p+1], z = src[3*p+2];
    float xhf, xlf, yhf, ylf, zhf, zlf, shf, tmp;
    const ushort xh = (ushort)bf16bits(x, xhf);
    const ushort xl = (ushort)bf16bits(x - xhf, xlf);
    const ushort yh = (ushort)bf16bits(y, yhf);
    const ushort yl = (ushort)bf16bits(y - yhf, ylf);
    const ushort zh = (ushort)bf16bits(z, zhf);
    const ushort zl = (ushort)bf16bits(z - zhf, zlf);
    const float s = fmaf(x, x, fmaf(y, y, z * z));
    const ushort sh = (ushort)bf16bits(s, shf);
    const ushort sl = (ushort)bf16bits(s - shf, tmp);
    const ushort m2xh = (ushort)bf16bits(-2.0f * xhf, tmp);
    const ushort m2xl = (ushort)bf16bits(-2.0f * xlf, tmp);
    const ushort m2yh = (ushort)bf16bits(-2.0f * yhf, tmp);
    const ushort m2yl = (ushort)bf16bits(-2.0f * ylf, tmp);
    const ushort m2zh = (ushort)bf16bits(-2.0f * zhf, tmp);
    const ushort m2zl = (ushort)bf16bits(-2.0f * zlf, tmp);
    const ushort ONE  = 0x3F80;           // 1.0 bf16
    const ushort BIAS = 0x4400;           // 512.0 bf16 (exact)

    const s16x8 a0 = {(short)m2xh,(short)m2xl,(short)m2xh,(short)m2xl,
                      (short)m2yh,(short)m2yl,(short)m2yh,(short)m2yl};
    const s16x8 a1 = {(short)m2zh,(short)m2zl,(short)m2zh,(short)m2zl,
                      (short)sh,  (short)sl,  (short)BIAS, 0};
    const s16x8 b0 = {(short)xh,(short)xh,(short)xl,(short)xl,
                      (short)yh,(short)yh,(short)yl,(short)yl};
    const s16x8 b1 = {(short)zh,(short)zh,(short)zl,(short)zl,
                      (short)ONE,(short)ONE,(short)ONE, 0};

    s16x8* A8 = (s16x8*)pA;
    s16x8* B8 = (s16x8*)pB;
    // A: fragment-linear per 32-target tile: chunk = tilebase*64 + khalf*32 + row
    const int c0 = (p & ~31) * 2 + (p & 31);
    A8[c0]      = a0;   // k-slots 0-7  (lanes 0-31)
    A8[c0 + 32] = a1;   // k-slots 8-15 (lanes 32-63)
    // B: point-major
    B8[2*p]     = b0;
    B8[2*p + 1] = b1;
    sq[p] = s;
}

// ---------- main MFMA kernel, both directions (blockIdx.z selects) ----------
__global__ __launch_bounds__(256)
void chamfer_mfma_kernel(const ushort* __restrict__ Ad1, const ushort* __restrict__ Bd1,
                         const float*  __restrict__ Sd1, unsigned int* __restrict__ Od1,
                         const ushort* __restrict__ Ad2, const ushort* __restrict__ Bd2,
                         const float*  __restrict__ Sd2, unsigned int* __restrict__ Od2,
                         int Np, int Mp) {
    const int z = blockIdx.z;
    const ushort* pA  = z ? Ad2 : Ad1;
    const ushort* pB  = z ? Bd2 : Bd1;
    const float*  sqq = z ? Sd2 : Sd1;
    unsigned int* out = z ? Od2 : Od1;

    const int tid  = threadIdx.x;
    const int lane = tid & 63;
    const int wid  = tid >> 6;
    const int qblock = blockIdx.x * QPB;        // flat over B*Np (QPB | Np)
    const int b = qblock / Np;
    const size_t gchunk = ((size_t)b * Mp + (size_t)blockIdx.y * TSLICE) * 2;
    const s16x8* gA8 = (const s16x8*)pA + gchunk;   // L2-resident, read direct

    // B fragments: 4 x 32 queries, loop-invariant in registers
    const int qw = qblock + wid * QPW;
    s16x8 bfr0, bfr1, bfr2, bfr3;
    {
        const int qb = qw + (lane & 31);
        const size_t hi = (size_t)(lane >> 5) * 8;
        bfr0 = *(const s16x8*)(pB + (size_t)(qb +  0) * 16 + hi);
        bfr1 = *(const s16x8*)(pB + (size_t)(qb + 32) * 16 + hi);
        bfr2 = *(const s16x8*)(pB + (size_t)(qb + 64) * 16 + hi);
        bfr3 = *(const s16x8*)(pB + (size_t)(qb + 96) * 16 + hi);
    }

    // Sentinel-init the 4 physical D tuples (their first fold is harmless).
    asm volatile(
        "v_mov_b32 v48, 0x7f7f7f7f\n\tv_mov_b32 v49, 0x7f7f7f7f\n\t"
        "v_mov_b32 v50, 0x7f7f7f7f\n\tv_mov_b32 v51, 0x7f7f7f7f\n\t"
        "v_mov_b32 v52, 0x7f7f7f7f\n\tv_mov_b32 v53, 0x7f7f7f7f\n\t"
        "v_mov_b32 v54, 0x7f7f7f7f\n\tv_mov_b32 v55, 0x7f7f7f7f\n\t"
        "v_mov_b32 v56, 0x7f7f7f7f\n\tv_mov_b32 v57, 0x7f7f7f7f\n\t"
        "v_mov_b32 v58, 0x7f7f7f7f\n\tv_mov_b32 v59, 0x7f7f7f7f\n\t"
        "v_mov_b32 v60, 0x7f7f7f7f\n\tv_mov_b32 v61, 0x7f7f7f7f\n\t"
        "v_mov_b32 v62, 0x7f7f7f7f\n\tv_mov_b32 v63, 0x7f7f7f7f\n\t"
        "v_mov_b32 v64, 0x7f7f7f7f\n\tv_mov_b32 v65, 0x7f7f7f7f\n\t"
        "v_mov_b32 v66, 0x7f7f7f7f\n\tv_mov_b32 v67, 0x7f7f7f7f\n\t"
        "v_mov_b32 v68, 0x7f7f7f7f\n\tv_mov_b32 v69, 0x7f7f7f7f\n\t"
        "v_mov_b32 v70, 0x7f7f7f7f\n\tv_mov_b32 v71, 0x7f7f7f7f\n\t"
        "v_mov_b32 v72, 0x7f7f7f7f\n\tv_mov_b32 v73, 0x7f7f7f7f\n\t"
        "v_mov_b32 v74, 0x7f7f7f7f\n\tv_mov_b32 v75, 0x7f7f7f7f\n\t"
        "v_mov_b32 v76, 0x7f7f7f7f\n\tv_mov_b32 v77, 0x7f7f7f7f\n\t"
        "v_mov_b32 v78, 0x7f7f7f7f\n\tv_mov_b32 v79, 0x7f7f7f7f\n\t"
        "v_mov_b32 v80, 0x7f7f7f7f\n\tv_mov_b32 v81, 0x7f7f7f7f\n\t"
        "v_mov_b32 v82, 0x7f7f7f7f\n\tv_mov_b32 v83, 0x7f7f7f7f\n\t"
        "v_mov_b32 v84, 0x7f7f7f7f\n\tv_mov_b32 v85, 0x7f7f7f7f\n\t"
        "v_mov_b32 v86, 0x7f7f7f7f\n\tv_mov_b32 v87, 0x7f7f7f7f\n\t"
        "v_mov_b32 v88, 0x7f7f7f7f\n\tv_mov_b32 v89, 0x7f7f7f7f\n\t"
        "v_mov_b32 v90, 0x7f7f7f7f\n\tv_mov_b32 v91, 0x7f7f7f7f\n\t"
        "v_mov_b32 v92, 0x7f7f7f7f\n\tv_mov_b32 v93, 0x7f7f7f7f\n\t"
        "v_mov_b32 v94, 0x7f7f7f7f\n\tv_mov_b32 v95, 0x7f7f7f7f\n\t"
        "v_mov_b32 v96, 0x7f7f7f7f\n\tv_mov_b32 v97, 0x7f7f7f7f\n\t"
        "v_mov_b32 v98, 0x7f7f7f7f\n\tv_mov_b32 v99, 0x7f7f7f7f\n\t"
        "v_mov_b32 v100, 0x7f7f7f7f\n\tv_mov_b32 v101, 0x7f7f7f7f\n\t"
        "v_mov_b32 v102, 0x7f7f7f7f\n\tv_mov_b32 v103, 0x7f7f7f7f\n\t"
        "v_mov_b32 v104, 0x7f7f7f7f\n\tv_mov_b32 v105, 0x7f7f7f7f\n\t"
        "v_mov_b32 v106, 0x7f7f7f7f\n\tv_mov_b32 v107, 0x7f7f7f7f\n\t"
        "v_mov_b32 v108, 0x7f7f7f7f\n\tv_mov_b32 v109, 0x7f7f7f7f\n\t"
        "v_mov_b32 v110, 0x7f7f7f7f\n\tv_mov_b32 v111, 0x7f7f7f7f"
        ::: "v48","v49","v50","v51","v52","v53","v54","v55",
            "v56","v57","v58","v59","v60","v61","v62","v63",
            "v64","v65","v66","v67","v68","v69","v70","v71",
            "v72","v73","v74","v75","v76","v77","v78","v79",
            "v80","v81","v82","v83","v84","v85","v86","v87",
            "v88","v89","v90","v91","v92","v93","v94","v95",
            "v96","v97","v98","v99","v100","v101","v102","v103",
            "v104","v105","v106","v107","v108","v109","v110","v111");

    u32 b0 = 0x7F7F7F7Fu, b1 = 0x7F7F7F7Fu, b2 = 0x7F7F7F7Fu, b3 = 0x7F7F7F7Fu;

    const int NT = TSLICE / 32;
    s16x8 a = gA8[lane];                     // first A fragment (L2)
    for (int t = 0; t < NT; ++t) {
        const int tn = (t + 1 < NT) ? (t + 1) : t;
        const s16x8 an = gA8[tn * 64 + lane];   // prefetch next A fragment (L2)
        step_f0(a, bfr0, b0);   // fold D(t-1,f0) then MFMA(t,f0)
        step_f1(a, bfr1, b1);
        step_f2(a, bfr2, b2);
        step_f3(a, bfr3, b3);
        a = an;
    }

    // One-time hazard guard, then fold the last iteration's 4 tuples.
    asm volatile("s_nop 7\n\ts_nop 7\n\ts_nop 7");
    fold_f0(b0); fold_f1(b1); fold_f2(b2); fold_f3(b3);

    u32 bests[4] = {b0, b1, b2, b3};
    #pragma unroll
    for (int f = 0; f < 4; ++f) {
        u32 bu = bests[f];
        const u32 other = __shfl_xor(bu, 32);                 // merge row halves
        bu = bu < other ? bu : other;
        const int q = qw + f * 32 + (lane & 31);
        float v = (__uint_as_float(bu) - 512.0f) + sqq[q];    // un-bias
        v = fmaxf(v, 0.0f);                                   // clamp: keep >= 0
        if (lane < 32) atomicMin(out + q, __float_as_uint(v));
    }
}

// ---------- fallback (round-2 VALU kernel) if ws too small ----------
#define FSLICE 512
#define FROWS  512
__global__ __launch_bounds__(256)
void chamfer_dir_kernel(const float* __restrict__ P, const float* __restrict__ Q,
                        unsigned int* __restrict__ out, int Np, int Mp) {
    __shared__ float4 lds[FSLICE];
    const int tid = threadIdx.x;
    const int rowBase = blockIdx.x * FROWS;
    const int b = rowBase / Np;
    const int slice0 = blockIdx.y * FSLICE;
    const float* qs = Q + ((size_t)b * Mp + slice0) * 3;
    #pragma unroll
    for (int i = tid; i < FSLICE; i += 256) {
        const float x = qs[3*i+0], y = qs[3*i+1], z = qs[3*i+2];
        lds[i] = make_float4(x, y, z, fmaf(x, x, fmaf(y, y, z * z)));
    }
    const int q0 = rowBase + tid, q1 = q0 + 256;
    const float* p0 = P + (size_t)q0 * 3;
    const float* p1 = P + (size_t)q1 * 3;
    const float x0=p0[0], y0=p0[1], z0=p0[2], x1=p1[0], y1=p1[1], z1=p1[2];
    const float m2x0=-2*x0, m2y0=-2*y0, m2z0=-2*z0, m2x1=-2*x1, m2y1=-2*y1, m2z1=-2*z1;
    const float sqp0 = fmaf(x0,x0,fmaf(y0,y0,z0*z0));
    const float sqp1 = fmaf(x1,x1,fmaf(y1,y1,z1*z1));
    __syncthreads();
    float best0 = 3.0e38f, best1 = 3.0e38f;
    #pragma unroll 4
    for (int j = 0; j < FSLICE; j += 2) {
        const float4 a = lds[j], c = lds[j+1];
        const float d00 = fmaf(m2x0,a.x,fmaf(m2y0,a.y,fmaf(m2z0,a.z,a.w)));
        const float d01 = fmaf(m2x0,c.x,fmaf(m2y0,c.y,fmaf(m2z0,c.z,c.w)));
        best0 = fminf(fminf(d00,d01), best0);
        const float d10 = fmaf(m2x1,a.x,fmaf(m2y1,a.y,fmaf(m2z1,a.z,a.w)));
        const float d11 = fmaf(m2x1,c.x,fmaf(m2y1,c.y,fmaf(m2z1,c.z,c.w)));
        best1 = fminf(fminf(d10,d11), best1);
    }
    atomicMin(out + q0, __float_as_uint(fmaxf(best0 + sqp0, 0.f)));
    atomicMin(out + q1, __float_as_uint(fmaxf(best1 + sqp1, 0.f)));
}

extern "C" void kernel_launch(void* const* d_in, const int* in_sizes, int n_in,
                              void* d_out, int out_size, void* d_ws, size_t ws_size,
                              hipStream_t stream) {
    const float* in1 = (const float*)d_in[0];   // [B, N, 3]
    const float* in2 = (const float*)d_in[1];   // [B, M, 3]
    const int B = 8;
    const int N = in_sizes[0] / (B * 3);
    const int M = in_sizes[1] / (B * 3);
    const int P1 = B * N, P2 = B * M;
    unsigned int* out = (unsigned int*)d_out;

    const size_t packBytes1 = (size_t)P1 * 32, packBytes2 = (size_t)P2 * 32;
    const size_t need = 2*packBytes1 + 2*packBytes2 + (size_t)(P1+P2)*4;

    if (ws_size >= need && N == M) {
        char* w = (char*)d_ws;
        ushort* A1 = (ushort*)(w);
        ushort* B1 = (ushort*)(w + packBytes1);
        ushort* A2 = (ushort*)(w + 2*packBytes1);
        ushort* B2 = (ushort*)(w + 2*packBytes1 + packBytes2);
        float*  S1 = (float*) (w + 2*packBytes1 + 2*packBytes2);
        float*  S2 = (float*) (w + 2*packBytes1 + 2*packBytes2 + (size_t)P1*4);

        pack_all_kernel<<<(P1 + P2 + 255)/256, 256, 0, stream>>>(
            in1, in2, A1, B1, S1, A2, B2, S2, out, P1, P2);

        // z=0: dist1 (queries=input1, targets=input2); z=1: dist2
        dim3 g(P1 / QPB, M / TSLICE, 2);
        chamfer_mfma_kernel<<<g, 256, 0, stream>>>(
            A2, B1, S1, out,        // dir 1
            A1, B2, S2, out + P1,   // dir 2
            N, M);
    } else {
        hipMemsetAsync(d_out, 0x7F, (size_t)out_size * sizeof(float), stream);
        dim3 g1(P1 / FROWS, M / FSLICE);
        chamfer_dir_kernel<<<g1, 256, 0, stream>>>(in1, in2, out, N, M);
        dim3 g2(P2 / FROWS, N / FSLICE);
        chamfer_dir_kernel<<<g2, 256, 0, stream>>>(in2, in1, out + P1, M, N);
    }
}